// Round 1
// baseline (560.932 us; speedup 1.0000x reference)
//
#include <hip/hip_runtime.h>

#define Bn 256
#define Sn 1024
#define Tn 64

__device__ __forceinline__ float wave_max_f(float v) {
  #pragma unroll
  for (int o = 32; o > 0; o >>= 1) v = fmaxf(v, __shfl_xor(v, o, 64));
  return v;
}
__device__ __forceinline__ float wave_sum_f(float v) {
  #pragma unroll
  for (int o = 32; o > 0; o >>= 1) v += __shfl_xor(v, o, 64);
  return v;
}

// Blocks 0..255: forward algorithm (one wave per batch, lane j owns alpha[j]).
// Blocks 256..511: gold path score (one wave per batch, lanes stride over t).
__global__ __launch_bounds__(64) void crf_fwd_gold(
    const float* __restrict__ em, const int* __restrict__ tags,
    const int* __restrict__ mask, const float* __restrict__ trans,
    const float* __restrict__ startt, const float* __restrict__ endt,
    float* __restrict__ ws) {
  const int bid = blockIdx.x;
  const int j = threadIdx.x;

  if (bid < Bn) {
    // ---------------- forward (log-partition) ----------------
    const int b = bid;
    const float* emb = em + (size_t)b * Sn * Tn;
    const int* mk = mask + (size_t)b * Sn;

    // F[i] = exp(trans[i][j]) : lane j holds column j of exp(transitions)
    float F[Tn];
    #pragma unroll
    for (int i = 0; i < Tn; ++i) F[i] = __expf(trans[i * Tn + j]);

    float alpha = startt[j] + emb[j];
    float m = wave_max_f(alpha);  // renorm reference, refreshed every 8 steps

    __shared__ __align__(16) float pbuf[2][Tn];

    // emissions prefetch pipeline, depth 3 (coalesced 256B per wave per step)
    float e0 = emb[1 * Tn + j];
    float e1 = emb[2 * Tn + j];
    float e2 = emb[3 * Tn + j];

    for (int t = 1; t < Sn; ++t) {
      float ecur = e0; e0 = e1; e1 = e2;
      if (t + 3 < Sn) e2 = emb[(size_t)(t + 3) * Tn + j];

      float p = __expf(alpha - m);
      float* pb = pbuf[t & 1];
      pb[j] = p;
      __syncthreads();  // single-wave block: cheap; double-buffer covers WAR

      float a0 = 0.f, a1 = 0.f, a2 = 0.f, a3 = 0.f;
      #pragma unroll
      for (int i = 0; i < Tn; i += 4) {
        float4 pv = *(const float4*)(pb + i);  // ds_read_b128 broadcast
        a0 = fmaf(pv.x, F[i + 0], a0);
        a1 = fmaf(pv.y, F[i + 1], a1);
        a2 = fmaf(pv.z, F[i + 2], a2);
        a3 = fmaf(pv.w, F[i + 3], a3);
      }
      float s = (a0 + a1) + (a2 + a3);
      float na = ecur + m + __logf(s);
      alpha = (mk[t] != 0) ? na : alpha;   // mask semantics (all-ones in bench)
      if ((t & 7) == 0) m = wave_max_f(alpha);
    }

    // log_Z = logsumexp(alpha + end_transitions)
    float v = alpha + endt[j];
    float mm = wave_max_f(v);
    float ss = wave_sum_f(__expf(v - mm));
    if (j == 0) ws[b] = mm + __logf(ss);
  } else {
    // ---------------- gold score ----------------
    const int b = bid - Bn;
    const float* emb = em + (size_t)b * Sn * Tn;
    const int* tg = tags + (size_t)b * Sn;
    const int* mk = mask + (size_t)b * Sn;

    float acc = 0.f;
    int msum = 0;
    for (int t = j; t < Sn; t += 64) {
      int mv = mk[t];
      msum += mv;
      if (t >= 1 && mv != 0) {
        int tp = tg[t - 1], tc = tg[t];
        acc += trans[tp * Tn + tc] + emb[(size_t)t * Tn + tc];
      }
    }
    #pragma unroll
    for (int o = 32; o > 0; o >>= 1) {
      acc += __shfl_xor(acc, o, 64);
      msum += __shfl_xor(msum, o, 64);
    }
    if (j == 0) {
      int t0 = tg[0];
      float sc = startt[t0] + emb[t0] + acc;
      int last = msum - 1;            // mask.sum() - 1
      sc += endt[tg[last]];
      ws[Bn + b] = sc;
    }
  }
}

__global__ __launch_bounds__(256) void crf_reduce(const float* __restrict__ ws,
                                                  float* __restrict__ out) {
  int i = threadIdx.x;  // 256 threads = 4 waves
  float v = ws[i] - ws[Bn + i];
  #pragma unroll
  for (int o = 32; o > 0; o >>= 1) v += __shfl_xor(v, o, 64);
  __shared__ float sb[4];
  if ((i & 63) == 0) sb[i >> 6] = v;
  __syncthreads();
  if (i == 0) out[0] = (sb[0] + sb[1] + sb[2] + sb[3]) * (1.0f / Bn);
}

extern "C" void kernel_launch(void* const* d_in, const int* in_sizes, int n_in,
                              void* d_out, int out_size, void* d_ws, size_t ws_size,
                              hipStream_t stream) {
  const float* em     = (const float*)d_in[0];
  const int*   tags   = (const int*)d_in[1];
  const int*   mask   = (const int*)d_in[2];
  const float* trans  = (const float*)d_in[3];
  const float* startt = (const float*)d_in[4];
  const float* endt   = (const float*)d_in[5];
  float* ws  = (float*)d_ws;
  float* out = (float*)d_out;

  crf_fwd_gold<<<2 * Bn, Tn, 0, stream>>>(em, tags, mask, trans, startt, endt, ws);
  crf_reduce<<<1, 256, 0, stream>>>(ws, out);
}